// Round 1
// baseline (677.172 us; speedup 1.0000x reference)
//
#include <hip/hip_runtime.h>
#include <cstdint>
#include <cstddef>

#define NB 8
#define NL 2048
#define TOPK 30
#define NH 128

// ---------------------------------------------------------------------------
// K1: pairwise distances + stable top-30 smallest per row.
// One block (256 threads) per row (b,i). Distances bit-exact vs numpy:
// ((dx*dx + dy*dy) + dz*dz) + 1e-6, correctly-rounded sqrt, all single-rounded.
// Selection key = (float_bits(D) << 32) | j  -> ascending (D, j) == lax.top_k
// stable tie-break (lower index first).
// ---------------------------------------------------------------------------
__global__ __launch_bounds__(256) void topk_kernel(
    const float* __restrict__ X, const float* __restrict__ mask,
    float* __restrict__ eidx, float* __restrict__ dnb)
{
    __shared__ float Drow[NL];
    __shared__ unsigned long long kred[5];
    __shared__ float fred[5];

    const int row = blockIdx.x;            // b*NL + i
    const int b   = row >> 11;
    const int i   = row & (NL - 1);
    const int tid = threadIdx.x;
    const int wv  = tid >> 6;
    const int ln  = tid & 63;

    const float* Xbatch = X + (size_t)b * NL * 12;   // (L,4,3)
    const float* Mrow   = mask + (size_t)b * NL;
    const float* pi     = Xbatch + ((size_t)i * 4 + 1) * 3;
    const float xi = pi[0], yi = pi[1], zi = pi[2];
    const float mi = Mrow[i];

    float lmax = 0.0f;
    for (int j = tid; j < NL; j += 256) {
        const float* pj = Xbatch + ((size_t)j * 4 + 1) * 3;
        float dx = xi - pj[0];
        float dy = yi - pj[1];
        float dz = zi - pj[2];
        float s = __fadd_rn(__fmul_rn(dx, dx), __fmul_rn(dy, dy));
        s = __fadd_rn(s, __fmul_rn(dz, dz));
        s = __fadd_rn(s, 1e-6f);
        float m2 = __fmul_rn(Mrow[j], mi);
        float d  = __fmul_rn(m2, __fsqrt_rn(s));
        Drow[j] = d;
        lmax = fmaxf(lmax, d);
    }
    #pragma unroll
    for (int off = 32; off; off >>= 1) lmax = fmaxf(lmax, __shfl_xor(lmax, off));
    if (ln == 0) fred[wv] = lmax;
    __syncthreads();
    if (tid == 0) fred[4] = fmaxf(fmaxf(fred[0], fred[1]), fmaxf(fred[2], fred[3]));
    __syncthreads();
    const float dmaxp1 = __fadd_rn(fred[4], 1.0f);
    for (int j = tid; j < NL; j += 256) {
        float m2 = __fmul_rn(Mrow[j], mi);
        Drow[j] = __fadd_rn(Drow[j], __fmul_rn(__fsub_rn(1.0f, m2), dmaxp1));
    }
    __syncthreads();

    unsigned long long last = 0ULL;   // all real keys > 0 (D >= 1e-3 or adjusted)
    float* eo  = eidx + (size_t)row * TOPK;
    float* dno = dnb  + (size_t)row * TOPK;
    for (int k = 0; k < TOPK; ++k) {
        unsigned long long best = ~0ULL;
        for (int j = tid; j < NL; j += 256) {
            unsigned long long key =
                ((unsigned long long)__float_as_uint(Drow[j]) << 32) | (unsigned)j;
            if (key > last && key < best) best = key;
        }
        #pragma unroll
        for (int off = 32; off; off >>= 1) {
            unsigned long long o = __shfl_xor(best, off);
            if (o < best) best = o;
        }
        if (ln == 0) kred[wv] = best;
        __syncthreads();
        if (tid == 0) {
            unsigned long long w = kred[0];
            if (kred[1] < w) w = kred[1];
            if (kred[2] < w) w = kred[2];
            if (kred[3] < w) w = kred[3];
            kred[4] = w;
            eo[k]  = (float)(unsigned)(w & 0xFFFFFFFFu);   // E_idx as float32
            dno[k] = __uint_as_float((unsigned)(w >> 32)); // selected D_adjust
        }
        __syncthreads();
        last = kred[4];
    }
}

// ---------------------------------------------------------------------------
// K2: edge features -> 32x128 matmul -> LayerNorm -> E.
// One wave per edge. Lanes 0..31 each compute one feature; broadcast via shfl.
// Each lane keeps two W_edge columns (h, h+64) in registers.
// ---------------------------------------------------------------------------
__global__ __launch_bounds__(256) void edge_kernel(
    const float* __restrict__ eidx, const float* __restrict__ dnb,
    const float* __restrict__ We, const float* __restrict__ be,
    const float* __restrict__ ge, const float* __restrict__ bte,
    float* __restrict__ E)
{
    const int lane = threadIdx.x & 63;
    const int wid  = (int)((blockIdx.x * blockDim.x + threadIdx.x) >> 6);
    const int nw   = (int)((gridDim.x * blockDim.x) >> 6);
    const int h0 = lane, h1 = lane + 64;

    float w0[32], w1[32];
    #pragma unroll
    for (int j = 0; j < 32; ++j) { w0[j] = We[j * NH + h0]; w1[j] = We[j * NH + h1]; }
    const float bb0 = be[h0],  bb1 = be[h1];
    const float g0  = ge[h0],  g1  = ge[h1];
    const float t0  = bte[h0], t1  = bte[h1];

    // per-lane feature constant: freq for lanes 0..15, RBF mu for 16..31
    float fc = 0.0f;
    if (lane < 16)      fc = expf((float)(2 * (lane & 7)) * -0.57564627f); // ln(1e4)/16
    else if (lane < 32) fc = (float)(lane - 16) * (20.0f / 15.0f);

    const int total = NB * NL * TOPK;
    for (int e = wid; e < total; e += nw) {
        const int row = e / TOPK;
        const int i   = row & (NL - 1);
        const float fidx = eidx[e];
        const float Dv   = dnb[e];

        float feat = 0.0f;
        if (lane < 8) {
            feat = cosf((fidx - (float)i) * fc);
        } else if (lane < 16) {
            feat = sinf((fidx - (float)i) * fc);
        } else if (lane < 32) {
            float t = (Dv - fc) * 0.8f;   // /1.25
            feat = expf(-t * t);
        }

        float a0 = bb0, a1 = bb1;
        #pragma unroll
        for (int j = 0; j < 32; ++j) {
            float ej = __shfl(feat, j);
            a0 = fmaf(ej, w0[j], a0);
            a1 = fmaf(ej, w1[j], a1);
        }
        // LayerNorm over 128 (2 values/lane x 64 lanes)
        float s  = a0 + a1;
        float s2 = fmaf(a0, a0, a1 * a1);
        #pragma unroll
        for (int off = 32; off; off >>= 1) {
            s  += __shfl_xor(s, off);
            s2 += __shfl_xor(s2, off);
        }
        float mean = s * (1.0f / 128.0f);
        float var  = fmaxf(s2 * (1.0f / 128.0f) - mean * mean, 0.0f);
        float inv  = rsqrtf(var + 1e-5f);
        float* o = E + (size_t)e * NH;
        o[h0] = (a0 - mean) * inv * g0 + t0;
        o[h1] = (a1 - mean) * inv * g1 + t1;
    }
}

// ---------------------------------------------------------------------------
// K3a: dihedral angle features (6 per node) into workspace.
// ---------------------------------------------------------------------------
__device__ __forceinline__ void loadPt(const float* XB, int t, float v[3]) {
    int r = t / 3, a = t - 3 * r;
    const float* p = XB + ((size_t)r * 4 + a) * 3;
    v[0] = p[0]; v[1] = p[1]; v[2] = p[2];
}
__device__ __forceinline__ void unit3(float v[3]) {
    float n = sqrtf(v[0]*v[0] + v[1]*v[1] + v[2]*v[2]) + 1e-8f;
    v[0] /= n; v[1] /= n; v[2] /= n;
}
__device__ __forceinline__ void cross3(const float a[3], const float b[3], float o[3]) {
    o[0] = a[1]*b[2] - a[2]*b[1];
    o[1] = a[2]*b[0] - a[0]*b[2];
    o[2] = a[0]*b[1] - a[1]*b[0];
}

__global__ __launch_bounds__(256) void dihedral_kernel(
    const float* __restrict__ X, float* __restrict__ nf)
{
    int node = blockIdx.x * blockDim.x + threadIdx.x;
    if (node >= NB * NL) return;
    int b = node >> 11, i = node & (NL - 1);
    const float* XB = X + (size_t)b * NL * 12;

    float ang[3];
    #pragma unroll
    for (int a = 0; a < 3; ++a) {
        int t = 3 * i - 1 + a;
        float an = 0.0f;
        if (t >= 0 && t <= 3 * NL - 4) {
            float p0[3], p1[3], p2[3], p3[3];
            loadPt(XB, t, p0); loadPt(XB, t + 1, p1);
            loadPt(XB, t + 2, p2); loadPt(XB, t + 3, p3);
            float u2[3], u1[3], u0[3];
            for (int c = 0; c < 3; ++c) {
                u2[c] = p1[c] - p0[c];
                u1[c] = p2[c] - p1[c];
                u0[c] = p3[c] - p2[c];
            }
            unit3(u2); unit3(u1); unit3(u0);
            float n2[3], n1[3];
            cross3(u2, u1, n2); cross3(u1, u0, n1);
            unit3(n2); unit3(n1);
            float cosD = n2[0]*n1[0] + n2[1]*n1[1] + n2[2]*n1[2];
            cosD = fminf(fmaxf(cosD, -1.0f + 1e-7f), 1.0f - 1e-7f);
            float sg = u2[0]*n1[0] + u2[1]*n1[1] + u2[2]*n1[2];
            float sgn = (sg > 0.0f) ? 1.0f : ((sg < 0.0f) ? -1.0f : 0.0f);
            an = sgn * acosf(cosD);
        }
        ang[a] = an;
    }
    float* o = nf + (size_t)node * 6;
    o[0] = cosf(ang[0]); o[1] = cosf(ang[1]); o[2] = cosf(ang[2]);
    o[3] = sinf(ang[0]); o[4] = sinf(ang[1]); o[5] = sinf(ang[2]);
}

// ---------------------------------------------------------------------------
// K3b: node 6x128 matmul + LayerNorm -> V. One wave per node.
// ---------------------------------------------------------------------------
__global__ __launch_bounds__(256) void node_kernel(
    const float* __restrict__ nf, const float* __restrict__ Wn,
    const float* __restrict__ bn, const float* __restrict__ gn,
    const float* __restrict__ btn, float* __restrict__ V)
{
    const int lane = threadIdx.x & 63;
    const int wid  = (int)((blockIdx.x * blockDim.x + threadIdx.x) >> 6);
    const int nw   = (int)((gridDim.x * blockDim.x) >> 6);
    const int h0 = lane, h1 = lane + 64;

    float w0[6], w1[6];
    #pragma unroll
    for (int j = 0; j < 6; ++j) { w0[j] = Wn[j * NH + h0]; w1[j] = Wn[j * NH + h1]; }
    const float bb0 = bn[h0],  bb1 = bn[h1];
    const float g0  = gn[h0],  g1  = gn[h1];
    const float t0  = btn[h0], t1  = btn[h1];

    for (int n = wid; n < NB * NL; n += nw) {
        float a0 = bb0, a1 = bb1;
        #pragma unroll
        for (int j = 0; j < 6; ++j) {
            float f = nf[(size_t)n * 6 + j];
            a0 = fmaf(f, w0[j], a0);
            a1 = fmaf(f, w1[j], a1);
        }
        float s  = a0 + a1;
        float s2 = fmaf(a0, a0, a1 * a1);
        #pragma unroll
        for (int off = 32; off; off >>= 1) {
            s  += __shfl_xor(s, off);
            s2 += __shfl_xor(s2, off);
        }
        float mean = s * (1.0f / 128.0f);
        float var  = fmaxf(s2 * (1.0f / 128.0f) - mean * mean, 0.0f);
        float inv  = rsqrtf(var + 1e-5f);
        float* o = V + (size_t)n * NH;
        o[h0] = (a0 - mean) * inv * g0 + t0;
        o[h1] = (a1 - mean) * inv * g1 + t1;
    }
}

extern "C" void kernel_launch(void* const* d_in, const int* in_sizes, int n_in,
                              void* d_out, int out_size, void* d_ws, size_t ws_size,
                              hipStream_t stream)
{
    const float* X    = (const float*)d_in[0];
    const float* mask = (const float*)d_in[1];
    const float* Wn   = (const float*)d_in[2];
    const float* bn   = (const float*)d_in[3];
    const float* We   = (const float*)d_in[4];
    const float* be   = (const float*)d_in[5];
    const float* gn   = (const float*)d_in[6];
    const float* btn  = (const float*)d_in[7];
    const float* ge   = (const float*)d_in[8];
    const float* bte  = (const float*)d_in[9];

    float* out = (float*)d_out;
    float* V   = out;                                   // (8,2048,128)
    float* E   = V  + (size_t)NB * NL * NH;             // (8,2048,30,128)
    float* EI  = E  + (size_t)NB * NL * TOPK * NH;      // (8,2048,30) as float

    float* dnb = (float*)d_ws;                          // D_neighbors scratch
    float* nf  = dnb + (size_t)NB * NL * TOPK;          // node features scratch

    hipLaunchKernelGGL(topk_kernel,     dim3(NB * NL),            dim3(256), 0, stream,
                       X, mask, EI, dnb);
    hipLaunchKernelGGL(dihedral_kernel, dim3((NB * NL + 255)/256), dim3(256), 0, stream,
                       X, nf);
    hipLaunchKernelGGL(edge_kernel,     dim3(2048),               dim3(256), 0, stream,
                       EI, dnb, We, be, ge, bte, E);
    hipLaunchKernelGGL(node_kernel,     dim3(64),                 dim3(256), 0, stream,
                       nf, Wn, bn, gn, btn, V);
}

// Round 2
// 497.954 us; speedup vs baseline: 1.3599x; 1.3599x over previous
//
#include <hip/hip_runtime.h>
#include <cstdint>
#include <cstddef>

#define NB 8
#define NL 2048
#define TOPK 30
#define NH 128
#define CAND_CAP 256

typedef unsigned long long ull;

// ---------------------------------------------------------------------------
// K1: pairwise distances + stable top-30 smallest per row via radix-select.
// One block (256 threads) per row (b,i). Distances bit-exact vs numpy:
// ((dx*dx + dy*dy) + dz*dz) + 1e-6, correctly-rounded sqrt, all single-rounded.
// Selection key = (float_bits(Dadj) << 32) | j -> ascending (D, j) == lax.top_k
// stable tie-break. Histogram on bits>>20 (monotone for positive floats) finds
// the cutoff bin containing the 30th element; only candidates in bins <= cutoff
// (typically ~30-60 of 2048) enter the exact argmin loop.
// ---------------------------------------------------------------------------
__global__ __launch_bounds__(256) void topk_kernel(
    const float* __restrict__ X, const float* __restrict__ mask,
    float* __restrict__ eidx, float* __restrict__ dnb)
{
    __shared__ unsigned int Drow[NL];     // D float bits, then Dadj bits
    __shared__ unsigned int hist[NL];     // 2048-bin histogram
    __shared__ ull  cand[CAND_CAP];
    __shared__ unsigned int partial[256];
    __shared__ unsigned int cutInfo[2];   // [0]=cut bin, [1]=count
    __shared__ unsigned int cntS;
    __shared__ float fred[5];
    __shared__ ull  kred[5];

    const int row = blockIdx.x;            // b*NL + i
    const int b   = row >> 11;
    const int i   = row & (NL - 1);
    const int tid = threadIdx.x;
    const int wv  = tid >> 6;
    const int ln  = tid & 63;

    const float* Xbatch = X + (size_t)b * NL * 12;   // (L,4,3)
    const float* Mrow   = mask + (size_t)b * NL;
    const float* pi     = Xbatch + ((size_t)i * 4 + 1) * 3;
    const float xi = pi[0], yi = pi[1], zi = pi[2];
    const float mi = Mrow[i];

    // ---- distances + row max; zero histogram ----
    float lmax = 0.0f;
    for (int j = tid; j < NL; j += 256) {
        const float* pj = Xbatch + ((size_t)j * 4 + 1) * 3;
        float dx = xi - pj[0];
        float dy = yi - pj[1];
        float dz = zi - pj[2];
        float s = __fadd_rn(__fmul_rn(dx, dx), __fmul_rn(dy, dy));
        s = __fadd_rn(s, __fmul_rn(dz, dz));
        s = __fadd_rn(s, 1e-6f);
        float m2 = __fmul_rn(Mrow[j], mi);
        float d  = __fmul_rn(m2, __fsqrt_rn(s));
        Drow[j] = __float_as_uint(d);
        hist[j] = 0u;
        lmax = fmaxf(lmax, d);
    }
    #pragma unroll
    for (int off = 32; off; off >>= 1) lmax = fmaxf(lmax, __shfl_xor(lmax, off));
    if (ln == 0) fred[wv] = lmax;
    __syncthreads();
    if (tid == 0) {
        fred[4] = fmaxf(fmaxf(fred[0], fred[1]), fmaxf(fred[2], fred[3]));
        cntS = 0u;
        cutInfo[0] = 0u; cutInfo[1] = 0u;
    }
    __syncthreads();

    // ---- adjust + histogram ----
    const float dmaxp1 = __fadd_rn(fred[4], 1.0f);
    for (int j = tid; j < NL; j += 256) {
        float m2 = __fmul_rn(Mrow[j], mi);
        float dadj = __fadd_rn(__uint_as_float(Drow[j]),
                               __fmul_rn(__fsub_rn(1.0f, m2), dmaxp1));
        unsigned int bits = __float_as_uint(dadj);
        Drow[j] = bits;
        atomicAdd(&hist[bits >> 20], 1u);
    }
    __syncthreads();

    // ---- block scan over 2048 bins to find cutoff ----
    unsigned int psum = 0;
    #pragma unroll
    for (int q = 0; q < 8; ++q) psum += hist[tid * 8 + q];
    partial[tid] = psum;
    __syncthreads();
    if (wv == 0) {
        unsigned int v0 = partial[ln * 4 + 0], v1 = partial[ln * 4 + 1];
        unsigned int v2 = partial[ln * 4 + 2], v3 = partial[ln * 4 + 3];
        unsigned int lsum = v0 + v1 + v2 + v3;
        unsigned int run = lsum;
        #pragma unroll
        for (int off = 1; off < 64; off <<= 1) {
            unsigned int o = __shfl_up(run, off);
            if (ln >= off) run += o;
        }
        unsigned int excl = run - lsum;
        partial[ln * 4 + 0] = excl;
        partial[ln * 4 + 1] = excl + v0;
        partial[ln * 4 + 2] = excl + v0 + v1;
        partial[ln * 4 + 3] = excl + v0 + v1 + v2;
    }
    __syncthreads();
    unsigned int p = partial[tid];
    if (p < TOPK && p + psum >= TOPK) {
        unsigned int run = p;
        #pragma unroll
        for (int q = 0; q < 8; ++q) {
            unsigned int h = hist[tid * 8 + q];
            if (run < TOPK && run + h >= TOPK) {
                cutInfo[0] = (unsigned)(tid * 8 + q);
                cutInfo[1] = run + h;      // total candidates
            }
            run += h;
        }
    }
    __syncthreads();
    const unsigned int cutBin = cutInfo[0];

    // ---- compact candidates ----
    for (int j = tid; j < NL; j += 256) {
        unsigned int bits = Drow[j];
        if ((bits >> 20) <= cutBin) {
            unsigned int pos = atomicAdd(&cntS, 1u);
            if (pos < CAND_CAP) cand[pos] = ((ull)bits << 32) | (unsigned)j;
        }
    }
    __syncthreads();
    const unsigned int cnt = cntS;

    float* eo  = eidx + (size_t)row * TOPK;
    float* dno = dnb  + (size_t)row * TOPK;

    if (cnt <= CAND_CAP) {
        // ---- exact selection over candidates, wave 0 only ----
        if (wv == 0) {
            ull k0 = (ln +   0u < cnt) ? cand[ln +   0] : ~0ULL;
            ull k1 = (ln +  64u < cnt) ? cand[ln +  64] : ~0ULL;
            ull k2 = (ln + 128u < cnt) ? cand[ln + 128] : ~0ULL;
            ull k3 = (ln + 192u < cnt) ? cand[ln + 192] : ~0ULL;
            ull last = 0ULL;
            for (int k = 0; k < TOPK; ++k) {
                ull best = ~0ULL;
                if (k0 > last && k0 < best) best = k0;
                if (k1 > last && k1 < best) best = k1;
                if (k2 > last && k2 < best) best = k2;
                if (k3 > last && k3 < best) best = k3;
                #pragma unroll
                for (int off = 32; off; off >>= 1) {
                    ull o = __shfl_xor(best, off);
                    if (o < best) best = o;
                }
                if (ln == 0) {
                    eo[k]  = (float)(unsigned)(best & 0xFFFFFFFFu);
                    dno[k] = __uint_as_float((unsigned)(best >> 32));
                }
                last = best;
            }
        }
    } else {
        // ---- fallback: exact block-wide iterative argmin over all 2048 ----
        ull last = 0ULL;
        for (int k = 0; k < TOPK; ++k) {
            ull best = ~0ULL;
            for (int j = tid; j < NL; j += 256) {
                ull key = ((ull)Drow[j] << 32) | (unsigned)j;
                if (key > last && key < best) best = key;
            }
            #pragma unroll
            for (int off = 32; off; off >>= 1) {
                ull o = __shfl_xor(best, off);
                if (o < best) best = o;
            }
            if (ln == 0) kred[wv] = best;
            __syncthreads();
            if (tid == 0) {
                ull w = kred[0];
                if (kred[1] < w) w = kred[1];
                if (kred[2] < w) w = kred[2];
                if (kred[3] < w) w = kred[3];
                kred[4] = w;
                eo[k]  = (float)(unsigned)(w & 0xFFFFFFFFu);
                dno[k] = __uint_as_float((unsigned)(w >> 32));
            }
            __syncthreads();
            last = kred[4];
        }
    }
}

// ---------------------------------------------------------------------------
// K2: edge features -> 32x128 matmul -> LayerNorm -> E.
// One wave per edge. Lanes 0..31 each compute one feature; broadcast via shfl.
// Each lane keeps two W_edge columns (h, h+64) in registers.
// ---------------------------------------------------------------------------
__global__ __launch_bounds__(256) void edge_kernel(
    const float* __restrict__ eidx, const float* __restrict__ dnb,
    const float* __restrict__ We, const float* __restrict__ be,
    const float* __restrict__ ge, const float* __restrict__ bte,
    float* __restrict__ E)
{
    const int lane = threadIdx.x & 63;
    const int wid  = (int)((blockIdx.x * blockDim.x + threadIdx.x) >> 6);
    const int nw   = (int)((gridDim.x * blockDim.x) >> 6);
    const int h0 = lane, h1 = lane + 64;

    float w0[32], w1[32];
    #pragma unroll
    for (int j = 0; j < 32; ++j) { w0[j] = We[j * NH + h0]; w1[j] = We[j * NH + h1]; }
    const float bb0 = be[h0],  bb1 = be[h1];
    const float g0  = ge[h0],  g1  = ge[h1];
    const float t0  = bte[h0], t1  = bte[h1];

    // per-lane feature constant: freq for lanes 0..15, RBF mu for 16..31
    float fc = 0.0f;
    if (lane < 16)      fc = expf((float)(2 * (lane & 7)) * -0.57564627f); // ln(1e4)/16
    else if (lane < 32) fc = (float)(lane - 16) * (20.0f / 15.0f);

    const int total = NB * NL * TOPK;
    for (int e = wid; e < total; e += nw) {
        const int row = e / TOPK;
        const int i   = row & (NL - 1);
        const float fidx = eidx[e];
        const float Dv   = dnb[e];

        float feat = 0.0f;
        if (lane < 8) {
            feat = cosf((fidx - (float)i) * fc);
        } else if (lane < 16) {
            feat = sinf((fidx - (float)i) * fc);
        } else if (lane < 32) {
            float t = (Dv - fc) * 0.8f;   // /1.25
            feat = expf(-t * t);
        }

        float a0 = bb0, a1 = bb1;
        #pragma unroll
        for (int j = 0; j < 32; ++j) {
            float ej = __shfl(feat, j);
            a0 = fmaf(ej, w0[j], a0);
            a1 = fmaf(ej, w1[j], a1);
        }
        // LayerNorm over 128 (2 values/lane x 64 lanes)
        float s  = a0 + a1;
        float s2 = fmaf(a0, a0, a1 * a1);
        #pragma unroll
        for (int off = 32; off; off >>= 1) {
            s  += __shfl_xor(s, off);
            s2 += __shfl_xor(s2, off);
        }
        float mean = s * (1.0f / 128.0f);
        float var  = fmaxf(s2 * (1.0f / 128.0f) - mean * mean, 0.0f);
        float inv  = rsqrtf(var + 1e-5f);
        float* o = E + (size_t)e * NH;
        o[h0] = (a0 - mean) * inv * g0 + t0;
        o[h1] = (a1 - mean) * inv * g1 + t1;
    }
}

// ---------------------------------------------------------------------------
// K3a: dihedral angle features (6 per node) into workspace.
// ---------------------------------------------------------------------------
__device__ __forceinline__ void loadPt(const float* XB, int t, float v[3]) {
    int r = t / 3, a = t - 3 * r;
    const float* p = XB + ((size_t)r * 4 + a) * 3;
    v[0] = p[0]; v[1] = p[1]; v[2] = p[2];
}
__device__ __forceinline__ void unit3(float v[3]) {
    float n = sqrtf(v[0]*v[0] + v[1]*v[1] + v[2]*v[2]) + 1e-8f;
    v[0] /= n; v[1] /= n; v[2] /= n;
}
__device__ __forceinline__ void cross3(const float a[3], const float b[3], float o[3]) {
    o[0] = a[1]*b[2] - a[2]*b[1];
    o[1] = a[2]*b[0] - a[0]*b[2];
    o[2] = a[0]*b[1] - a[1]*b[0];
}

__global__ __launch_bounds__(256) void dihedral_kernel(
    const float* __restrict__ X, float* __restrict__ nf)
{
    int node = blockIdx.x * blockDim.x + threadIdx.x;
    if (node >= NB * NL) return;
    int b = node >> 11, i = node & (NL - 1);
    const float* XB = X + (size_t)b * NL * 12;

    float ang[3];
    #pragma unroll
    for (int a = 0; a < 3; ++a) {
        int t = 3 * i - 1 + a;
        float an = 0.0f;
        if (t >= 0 && t <= 3 * NL - 4) {
            float p0[3], p1[3], p2[3], p3[3];
            loadPt(XB, t, p0); loadPt(XB, t + 1, p1);
            loadPt(XB, t + 2, p2); loadPt(XB, t + 3, p3);
            float u2[3], u1[3], u0[3];
            for (int c = 0; c < 3; ++c) {
                u2[c] = p1[c] - p0[c];
                u1[c] = p2[c] - p1[c];
                u0[c] = p3[c] - p2[c];
            }
            unit3(u2); unit3(u1); unit3(u0);
            float n2[3], n1[3];
            cross3(u2, u1, n2); cross3(u1, u0, n1);
            unit3(n2); unit3(n1);
            float cosD = n2[0]*n1[0] + n2[1]*n1[1] + n2[2]*n1[2];
            cosD = fminf(fmaxf(cosD, -1.0f + 1e-7f), 1.0f - 1e-7f);
            float sg = u2[0]*n1[0] + u2[1]*n1[1] + u2[2]*n1[2];
            float sgn = (sg > 0.0f) ? 1.0f : ((sg < 0.0f) ? -1.0f : 0.0f);
            an = sgn * acosf(cosD);
        }
        ang[a] = an;
    }
    float* o = nf + (size_t)node * 6;
    o[0] = cosf(ang[0]); o[1] = cosf(ang[1]); o[2] = cosf(ang[2]);
    o[3] = sinf(ang[0]); o[4] = sinf(ang[1]); o[5] = sinf(ang[2]);
}

// ---------------------------------------------------------------------------
// K3b: node 6x128 matmul + LayerNorm -> V. One wave per node.
// ---------------------------------------------------------------------------
__global__ __launch_bounds__(256) void node_kernel(
    const float* __restrict__ nf, const float* __restrict__ Wn,
    const float* __restrict__ bn, const float* __restrict__ gn,
    const float* __restrict__ btn, float* __restrict__ V)
{
    const int lane = threadIdx.x & 63;
    const int wid  = (int)((blockIdx.x * blockDim.x + threadIdx.x) >> 6);
    const int nw   = (int)((gridDim.x * blockDim.x) >> 6);
    const int h0 = lane, h1 = lane + 64;

    float w0[6], w1[6];
    #pragma unroll
    for (int j = 0; j < 6; ++j) { w0[j] = Wn[j * NH + h0]; w1[j] = Wn[j * NH + h1]; }
    const float bb0 = bn[h0],  bb1 = bn[h1];
    const float g0  = gn[h0],  g1  = gn[h1];
    const float t0  = btn[h0], t1  = btn[h1];

    for (int n = wid; n < NB * NL; n += nw) {
        float a0 = bb0, a1 = bb1;
        #pragma unroll
        for (int j = 0; j < 6; ++j) {
            float f = nf[(size_t)n * 6 + j];
            a0 = fmaf(f, w0[j], a0);
            a1 = fmaf(f, w1[j], a1);
        }
        float s  = a0 + a1;
        float s2 = fmaf(a0, a0, a1 * a1);
        #pragma unroll
        for (int off = 32; off; off >>= 1) {
            s  += __shfl_xor(s, off);
            s2 += __shfl_xor(s2, off);
        }
        float mean = s * (1.0f / 128.0f);
        float var  = fmaxf(s2 * (1.0f / 128.0f) - mean * mean, 0.0f);
        float inv  = rsqrtf(var + 1e-5f);
        float* o = V + (size_t)n * NH;
        o[h0] = (a0 - mean) * inv * g0 + t0;
        o[h1] = (a1 - mean) * inv * g1 + t1;
    }
}

extern "C" void kernel_launch(void* const* d_in, const int* in_sizes, int n_in,
                              void* d_out, int out_size, void* d_ws, size_t ws_size,
                              hipStream_t stream)
{
    const float* X    = (const float*)d_in[0];
    const float* mask = (const float*)d_in[1];
    const float* Wn   = (const float*)d_in[2];
    const float* bn   = (const float*)d_in[3];
    const float* We   = (const float*)d_in[4];
    const float* be   = (const float*)d_in[5];
    const float* gn   = (const float*)d_in[6];
    const float* btn  = (const float*)d_in[7];
    const float* ge   = (const float*)d_in[8];
    const float* bte  = (const float*)d_in[9];

    float* out = (float*)d_out;
    float* V   = out;                                   // (8,2048,128)
    float* E   = V  + (size_t)NB * NL * NH;             // (8,2048,30,128)
    float* EI  = E  + (size_t)NB * NL * TOPK * NH;      // (8,2048,30) as float

    float* dnb = (float*)d_ws;                          // D_neighbors scratch
    float* nf  = dnb + (size_t)NB * NL * TOPK;          // node features scratch

    hipLaunchKernelGGL(topk_kernel,     dim3(NB * NL),            dim3(256), 0, stream,
                       X, mask, EI, dnb);
    hipLaunchKernelGGL(dihedral_kernel, dim3((NB * NL + 255)/256), dim3(256), 0, stream,
                       X, nf);
    hipLaunchKernelGGL(edge_kernel,     dim3(2048),               dim3(256), 0, stream,
                       EI, dnb, We, be, ge, bte, E);
    hipLaunchKernelGGL(node_kernel,     dim3(64),                 dim3(256), 0, stream,
                       nf, Wn, bn, gn, btn, V);
}

// Round 3
// 296.380 us; speedup vs baseline: 2.2848x; 1.6801x over previous
//
#include <hip/hip_runtime.h>
#include <cstdint>
#include <cstddef>

#define NB 8
#define NL 2048
#define TOPK 30
#define NH 128
#define CAND_CAP 256

typedef unsigned long long ull;
typedef __attribute__((ext_vector_type(8))) short short8v;   // 8 bf16
typedef __attribute__((ext_vector_type(4))) float f32x4;

__device__ __forceinline__ short f2bf(float f) {
    unsigned int b = __float_as_uint(f);
    b += 0x7fffu + ((b >> 16) & 1u);          // round-to-nearest-even
    return (short)(b >> 16);
}

// ---------------------------------------------------------------------------
// K1: pairwise distances + stable top-30 smallest per row via radix-select.
// (unchanged from R1 — bit-exact distances, histogram cutoff, exact argmin
// over compacted candidates, full fallback if candidates overflow)
// ---------------------------------------------------------------------------
__global__ __launch_bounds__(256) void topk_kernel(
    const float* __restrict__ X, const float* __restrict__ mask,
    float* __restrict__ eidx, float* __restrict__ dnb)
{
    __shared__ unsigned int Drow[NL];
    __shared__ unsigned int hist[NL];
    __shared__ ull  cand[CAND_CAP];
    __shared__ unsigned int partial[256];
    __shared__ unsigned int cutInfo[2];
    __shared__ unsigned int cntS;
    __shared__ float fred[5];
    __shared__ ull  kred[5];

    const int row = blockIdx.x;            // b*NL + i
    const int b   = row >> 11;
    const int i   = row & (NL - 1);
    const int tid = threadIdx.x;
    const int wv  = tid >> 6;
    const int ln  = tid & 63;

    const float* Xbatch = X + (size_t)b * NL * 12;
    const float* Mrow   = mask + (size_t)b * NL;
    const float* pi     = Xbatch + ((size_t)i * 4 + 1) * 3;
    const float xi = pi[0], yi = pi[1], zi = pi[2];
    const float mi = Mrow[i];

    float lmax = 0.0f;
    for (int j = tid; j < NL; j += 256) {
        const float* pj = Xbatch + ((size_t)j * 4 + 1) * 3;
        float dx = xi - pj[0];
        float dy = yi - pj[1];
        float dz = zi - pj[2];
        float s = __fadd_rn(__fmul_rn(dx, dx), __fmul_rn(dy, dy));
        s = __fadd_rn(s, __fmul_rn(dz, dz));
        s = __fadd_rn(s, 1e-6f);
        float m2 = __fmul_rn(Mrow[j], mi);
        float d  = __fmul_rn(m2, __fsqrt_rn(s));
        Drow[j] = __float_as_uint(d);
        hist[j] = 0u;
        lmax = fmaxf(lmax, d);
    }
    #pragma unroll
    for (int off = 32; off; off >>= 1) lmax = fmaxf(lmax, __shfl_xor(lmax, off));
    if (ln == 0) fred[wv] = lmax;
    __syncthreads();
    if (tid == 0) {
        fred[4] = fmaxf(fmaxf(fred[0], fred[1]), fmaxf(fred[2], fred[3]));
        cntS = 0u;
        cutInfo[0] = 0u; cutInfo[1] = 0u;
    }
    __syncthreads();

    const float dmaxp1 = __fadd_rn(fred[4], 1.0f);
    for (int j = tid; j < NL; j += 256) {
        float m2 = __fmul_rn(Mrow[j], mi);
        float dadj = __fadd_rn(__uint_as_float(Drow[j]),
                               __fmul_rn(__fsub_rn(1.0f, m2), dmaxp1));
        unsigned int bits = __float_as_uint(dadj);
        Drow[j] = bits;
        atomicAdd(&hist[bits >> 20], 1u);
    }
    __syncthreads();

    unsigned int psum = 0;
    #pragma unroll
    for (int q = 0; q < 8; ++q) psum += hist[tid * 8 + q];
    partial[tid] = psum;
    __syncthreads();
    if (wv == 0) {
        unsigned int v0 = partial[ln * 4 + 0], v1 = partial[ln * 4 + 1];
        unsigned int v2 = partial[ln * 4 + 2], v3 = partial[ln * 4 + 3];
        unsigned int lsum = v0 + v1 + v2 + v3;
        unsigned int run = lsum;
        #pragma unroll
        for (int off = 1; off < 64; off <<= 1) {
            unsigned int o = __shfl_up(run, off);
            if (ln >= off) run += o;
        }
        unsigned int excl = run - lsum;
        partial[ln * 4 + 0] = excl;
        partial[ln * 4 + 1] = excl + v0;
        partial[ln * 4 + 2] = excl + v0 + v1;
        partial[ln * 4 + 3] = excl + v0 + v1 + v2;
    }
    __syncthreads();
    unsigned int p = partial[tid];
    if (p < TOPK && p + psum >= TOPK) {
        unsigned int run = p;
        #pragma unroll
        for (int q = 0; q < 8; ++q) {
            unsigned int h = hist[tid * 8 + q];
            if (run < TOPK && run + h >= TOPK) {
                cutInfo[0] = (unsigned)(tid * 8 + q);
                cutInfo[1] = run + h;
            }
            run += h;
        }
    }
    __syncthreads();
    const unsigned int cutBin = cutInfo[0];

    for (int j = tid; j < NL; j += 256) {
        unsigned int bits = Drow[j];
        if ((bits >> 20) <= cutBin) {
            unsigned int pos = atomicAdd(&cntS, 1u);
            if (pos < CAND_CAP) cand[pos] = ((ull)bits << 32) | (unsigned)j;
        }
    }
    __syncthreads();
    const unsigned int cnt = cntS;

    float* eo  = eidx + (size_t)row * TOPK;
    float* dno = dnb  + (size_t)row * TOPK;

    if (cnt <= CAND_CAP) {
        if (wv == 0) {
            ull k0 = (ln +   0u < cnt) ? cand[ln +   0] : ~0ULL;
            ull k1 = (ln +  64u < cnt) ? cand[ln +  64] : ~0ULL;
            ull k2 = (ln + 128u < cnt) ? cand[ln + 128] : ~0ULL;
            ull k3 = (ln + 192u < cnt) ? cand[ln + 192] : ~0ULL;
            ull last = 0ULL;
            for (int k = 0; k < TOPK; ++k) {
                ull best = ~0ULL;
                if (k0 > last && k0 < best) best = k0;
                if (k1 > last && k1 < best) best = k1;
                if (k2 > last && k2 < best) best = k2;
                if (k3 > last && k3 < best) best = k3;
                #pragma unroll
                for (int off = 32; off; off >>= 1) {
                    ull o = __shfl_xor(best, off);
                    if (o < best) best = o;
                }
                if (ln == 0) {
                    eo[k]  = (float)(unsigned)(best & 0xFFFFFFFFu);
                    dno[k] = __uint_as_float((unsigned)(best >> 32));
                }
                last = best;
            }
        }
    } else {
        ull last = 0ULL;
        for (int k = 0; k < TOPK; ++k) {
            ull best = ~0ULL;
            for (int j = tid; j < NL; j += 256) {
                ull key = ((ull)Drow[j] << 32) | (unsigned)j;
                if (key > last && key < best) best = key;
            }
            #pragma unroll
            for (int off = 32; off; off >>= 1) {
                ull o = __shfl_xor(best, off);
                if (o < best) best = o;
            }
            if (ln == 0) kred[wv] = best;
            __syncthreads();
            if (tid == 0) {
                ull w = kred[0];
                if (kred[1] < w) w = kred[1];
                if (kred[2] < w) w = kred[2];
                if (kred[3] < w) w = kred[3];
                kred[4] = w;
                eo[k]  = (float)(unsigned)(w & 0xFFFFFFFFu);
                dno[k] = __uint_as_float((unsigned)(w >> 32));
            }
            __syncthreads();
            last = kred[4];
        }
    }
}

// ---------------------------------------------------------------------------
// K2: edge features -> 32x128 matmul (MFMA bf16) -> LayerNorm -> E.
// One wave per 16-edge tile. A-frag: lane (c=lane&15, g=lane>>4) computes
// features k=g*8+e for edge tile_base+c (no shuffles). B-frag: W_edge bf16,
// loaded once per wave, reused across tiles. C/D: col=lane&15,
// row=(lane>>4)*4+j  -> LayerNorm = 4x shfl_xor within 16-lane groups.
// ---------------------------------------------------------------------------
__global__ __launch_bounds__(256) void edge_kernel(
    const float* __restrict__ eidx, const float* __restrict__ dnb,
    const float* __restrict__ We, const float* __restrict__ be,
    const float* __restrict__ ge, const float* __restrict__ bte,
    float* __restrict__ E)
{
    const int lane = threadIdx.x & 63;
    const int c    = lane & 15;        // A-row (edge) / D-col
    const int g    = lane >> 4;        // k-group
    const int wid  = (int)((blockIdx.x * blockDim.x + threadIdx.x) >> 6);
    const int nw   = (int)((gridDim.x * blockDim.x) >> 6);

    // B fragments: B[t][e] = We[g*8+e][t*16+c] as bf16
    short8v B[8];
    #pragma unroll
    for (int t = 0; t < 8; ++t)
        #pragma unroll
        for (int e = 0; e < 8; ++e)
            B[t][e] = f2bf(We[(g * 8 + e) * NH + t * 16 + c]);

    float bias[8], gam[8], bet[8];
    #pragma unroll
    for (int t = 0; t < 8; ++t) {
        bias[t] = be [t * 16 + c];
        gam[t]  = ge [t * 16 + c];
        bet[t]  = bte[t * 16 + c];
    }

    // per-lane feature constants for k = g*8+e
    float fcs[8];
    #pragma unroll
    for (int e = 0; e < 8; ++e) {
        if (g < 2) fcs[e] = expf((float)(2 * e) * -0.57564627f);  // ln(1e4)/16
        else       fcs[e] = (float)((g - 2) * 8 + e) * (20.0f / 15.0f);
    }

    const int ntiles = NB * NL * TOPK / 16;
    for (int tile = wid; tile < ntiles; tile += nw) {
        const int e0 = tile * 16;
        const int eg = e0 + c;
        const float fidx = eidx[eg];
        const float Dv   = dnb[eg];
        const int   row  = eg / TOPK;
        const float d    = fidx - (float)(row & (NL - 1));

        short8v A;
        if (g == 0) {
            #pragma unroll
            for (int e = 0; e < 8; ++e) A[e] = f2bf(cosf(d * fcs[e]));
        } else if (g == 1) {
            #pragma unroll
            for (int e = 0; e < 8; ++e) A[e] = f2bf(sinf(d * fcs[e]));
        } else {
            #pragma unroll
            for (int e = 0; e < 8; ++e) {
                float tt = (Dv - fcs[e]) * 0.8f;
                A[e] = f2bf(expf(-tt * tt));
            }
        }

        f32x4 acc[8];
        const f32x4 zero = {0.0f, 0.0f, 0.0f, 0.0f};
        #pragma unroll
        for (int t = 0; t < 8; ++t)
            acc[t] = __builtin_amdgcn_mfma_f32_16x16x32_bf16(A, B[t], zero, 0, 0, 0);

        float s[4]  = {0, 0, 0, 0};
        float s2[4] = {0, 0, 0, 0};
        #pragma unroll
        for (int t = 0; t < 8; ++t)
            #pragma unroll
            for (int j = 0; j < 4; ++j) {
                float v = acc[t][j] + bias[t];
                acc[t][j] = v;
                s[j]  += v;
                s2[j] = fmaf(v, v, s2[j]);
            }
        #pragma unroll
        for (int j = 0; j < 4; ++j)
            #pragma unroll
            for (int off = 1; off < 16; off <<= 1) {
                s[j]  += __shfl_xor(s[j],  off);
                s2[j] += __shfl_xor(s2[j], off);
            }
        float mean[4], inv[4];
        #pragma unroll
        for (int j = 0; j < 4; ++j) {
            mean[j] = s[j] * (1.0f / 128.0f);
            float var = fmaxf(s2[j] * (1.0f / 128.0f) - mean[j] * mean[j], 0.0f);
            inv[j] = rsqrtf(var + 1e-5f);
        }
        #pragma unroll
        for (int t = 0; t < 8; ++t)
            #pragma unroll
            for (int j = 0; j < 4; ++j) {
                float v = (acc[t][j] - mean[j]) * inv[j] * gam[t] + bet[t];
                __builtin_nontemporal_store(
                    v, &E[(size_t)(e0 + g * 4 + j) * NH + t * 16 + c]);
            }
    }
}

// ---------------------------------------------------------------------------
// K3a: dihedral angle features (6 per node) into workspace.
// ---------------------------------------------------------------------------
__device__ __forceinline__ void loadPt(const float* XB, int t, float v[3]) {
    int r = t / 3, a = t - 3 * r;
    const float* p = XB + ((size_t)r * 4 + a) * 3;
    v[0] = p[0]; v[1] = p[1]; v[2] = p[2];
}
__device__ __forceinline__ void unit3(float v[3]) {
    float n = sqrtf(v[0]*v[0] + v[1]*v[1] + v[2]*v[2]) + 1e-8f;
    v[0] /= n; v[1] /= n; v[2] /= n;
}
__device__ __forceinline__ void cross3(const float a[3], const float b[3], float o[3]) {
    o[0] = a[1]*b[2] - a[2]*b[1];
    o[1] = a[2]*b[0] - a[0]*b[2];
    o[2] = a[0]*b[1] - a[1]*b[0];
}

__global__ __launch_bounds__(256) void dihedral_kernel(
    const float* __restrict__ X, float* __restrict__ nf)
{
    int node = blockIdx.x * blockDim.x + threadIdx.x;
    if (node >= NB * NL) return;
    int b = node >> 11, i = node & (NL - 1);
    const float* XB = X + (size_t)b * NL * 12;

    float ang[3];
    #pragma unroll
    for (int a = 0; a < 3; ++a) {
        int t = 3 * i - 1 + a;
        float an = 0.0f;
        if (t >= 0 && t <= 3 * NL - 4) {
            float p0[3], p1[3], p2[3], p3[3];
            loadPt(XB, t, p0); loadPt(XB, t + 1, p1);
            loadPt(XB, t + 2, p2); loadPt(XB, t + 3, p3);
            float u2[3], u1[3], u0[3];
            for (int cc = 0; cc < 3; ++cc) {
                u2[cc] = p1[cc] - p0[cc];
                u1[cc] = p2[cc] - p1[cc];
                u0[cc] = p3[cc] - p2[cc];
            }
            unit3(u2); unit3(u1); unit3(u0);
            float n2[3], n1[3];
            cross3(u2, u1, n2); cross3(u1, u0, n1);
            unit3(n2); unit3(n1);
            float cosD = n2[0]*n1[0] + n2[1]*n1[1] + n2[2]*n1[2];
            cosD = fminf(fmaxf(cosD, -1.0f + 1e-7f), 1.0f - 1e-7f);
            float sg = u2[0]*n1[0] + u2[1]*n1[1] + u2[2]*n1[2];
            float sgn = (sg > 0.0f) ? 1.0f : ((sg < 0.0f) ? -1.0f : 0.0f);
            an = sgn * acosf(cosD);
        }
        ang[a] = an;
    }
    float* o = nf + (size_t)node * 6;
    o[0] = cosf(ang[0]); o[1] = cosf(ang[1]); o[2] = cosf(ang[2]);
    o[3] = sinf(ang[0]); o[4] = sinf(ang[1]); o[5] = sinf(ang[2]);
}

// ---------------------------------------------------------------------------
// K3b: node 6x128 matmul + LayerNorm -> V. One wave per node.
// ---------------------------------------------------------------------------
__global__ __launch_bounds__(256) void node_kernel(
    const float* __restrict__ nf, const float* __restrict__ Wn,
    const float* __restrict__ bn, const float* __restrict__ gn,
    const float* __restrict__ btn, float* __restrict__ V)
{
    const int lane = threadIdx.x & 63;
    const int wid  = (int)((blockIdx.x * blockDim.x + threadIdx.x) >> 6);
    const int nw   = (int)((gridDim.x * blockDim.x) >> 6);
    const int h0 = lane, h1 = lane + 64;

    float w0[6], w1[6];
    #pragma unroll
    for (int j = 0; j < 6; ++j) { w0[j] = Wn[j * NH + h0]; w1[j] = Wn[j * NH + h1]; }
    const float bb0 = bn[h0],  bb1 = bn[h1];
    const float g0  = gn[h0],  g1  = gn[h1];
    const float t0  = btn[h0], t1  = btn[h1];

    for (int n = wid; n < NB * NL; n += nw) {
        float a0 = bb0, a1 = bb1;
        #pragma unroll
        for (int j = 0; j < 6; ++j) {
            float f = nf[(size_t)n * 6 + j];
            a0 = fmaf(f, w0[j], a0);
            a1 = fmaf(f, w1[j], a1);
        }
        float s  = a0 + a1;
        float s2 = fmaf(a0, a0, a1 * a1);
        #pragma unroll
        for (int off = 32; off; off >>= 1) {
            s  += __shfl_xor(s, off);
            s2 += __shfl_xor(s2, off);
        }
        float mean = s * (1.0f / 128.0f);
        float var  = fmaxf(s2 * (1.0f / 128.0f) - mean * mean, 0.0f);
        float inv  = rsqrtf(var + 1e-5f);
        float* o = V + (size_t)n * NH;
        o[h0] = (a0 - mean) * inv * g0 + t0;
        o[h1] = (a1 - mean) * inv * g1 + t1;
    }
}

extern "C" void kernel_launch(void* const* d_in, const int* in_sizes, int n_in,
                              void* d_out, int out_size, void* d_ws, size_t ws_size,
                              hipStream_t stream)
{
    const float* X    = (const float*)d_in[0];
    const float* mask = (const float*)d_in[1];
    const float* Wn   = (const float*)d_in[2];
    const float* bn   = (const float*)d_in[3];
    const float* We   = (const float*)d_in[4];
    const float* be   = (const float*)d_in[5];
    const float* gn   = (const float*)d_in[6];
    const float* btn  = (const float*)d_in[7];
    const float* ge   = (const float*)d_in[8];
    const float* bte  = (const float*)d_in[9];

    float* out = (float*)d_out;
    float* V   = out;                                   // (8,2048,128)
    float* E   = V  + (size_t)NB * NL * NH;             // (8,2048,30,128)
    float* EI  = E  + (size_t)NB * NL * TOPK * NH;      // (8,2048,30) as float

    float* dnb = (float*)d_ws;                          // D_neighbors scratch
    float* nf  = dnb + (size_t)NB * NL * TOPK;          // node features scratch

    hipLaunchKernelGGL(topk_kernel,     dim3(NB * NL),             dim3(256), 0, stream,
                       X, mask, EI, dnb);
    hipLaunchKernelGGL(dihedral_kernel, dim3((NB * NL + 255)/256), dim3(256), 0, stream,
                       X, nf);
    hipLaunchKernelGGL(edge_kernel,     dim3(1920),                dim3(256), 0, stream,
                       EI, dnb, We, be, ge, bte, E);
    hipLaunchKernelGGL(node_kernel,     dim3(64),                  dim3(256), 0, stream,
                       nf, Wn, bn, gn, btn, V);
}

// Round 4
// 240.151 us; speedup vs baseline: 2.8198x; 1.2341x over previous
//
#include <hip/hip_runtime.h>
#include <cstdint>
#include <cstddef>

#define NB 8
#define NL 2048
#define TOPK 30
#define NH 128
#define CAND_CAP 256
#define BINS 1024

typedef unsigned long long ull;
typedef __attribute__((ext_vector_type(8))) short short8v;   // 8 bf16
typedef __attribute__((ext_vector_type(4))) float f32x4;

__device__ __forceinline__ short f2bf(float f) {
    unsigned int b = __float_as_uint(f);
    b += 0x7fffu + ((b >> 16) & 1u);          // round-to-nearest-even
    return (short)(b >> 16);
}

// bit-exact distance vs numpy: ((dx*dx+dy*dy)+dz*dz)+1e-6, rn sqrt
__device__ __forceinline__ float calc_d(const float* __restrict__ Xs,
                                        const float* __restrict__ Mrow, int j,
                                        float xi, float yi, float zi, float mi) {
    float dx = xi - Xs[j * 3 + 0];
    float dy = yi - Xs[j * 3 + 1];
    float dz = zi - Xs[j * 3 + 2];
    float s = __fadd_rn(__fmul_rn(dx, dx), __fmul_rn(dy, dy));
    s = __fadd_rn(s, __fmul_rn(dz, dz));
    s = __fadd_rn(s, 1e-6f);
    float m2 = __fmul_rn(Mrow[j], mi);
    return __fmul_rn(m2, __fsqrt_rn(s));
}
__device__ __forceinline__ unsigned int calc_adj_bits(
    const float* __restrict__ Xs, const float* __restrict__ Mrow, int j,
    float xi, float yi, float zi, float mi, float dmaxp1) {
    float d  = calc_d(Xs, Mrow, j, xi, yi, zi, mi);
    float m2 = __fmul_rn(Mrow[j], mi);
    return __float_as_uint(__fadd_rn(d, __fmul_rn(__fsub_rn(1.0f, m2), dmaxp1)));
}

// ---------------------------------------------------------------------------
// K1: one WAVE per row. Block = 4 rows of one batch; CA coords staged to LDS
// once (single barrier), then per-wave: max-reduce, 1024-bin radix histogram,
// shuffle scan -> cutoff, ballot compaction, rank-based exact selection.
// ---------------------------------------------------------------------------
__global__ __launch_bounds__(256) void topk_kernel(
    const float* __restrict__ X, const float* __restrict__ mask,
    float* __restrict__ eidx, float* __restrict__ dnb)
{
    __shared__ float Xs[NL * 3];                   // 24 KB
    __shared__ unsigned int hist[4][BINS];         // 16 KB
    __shared__ ull cand[4][CAND_CAP];              // 8 KB

    const int tid = threadIdx.x;
    const int wv  = tid >> 6;
    const int ln  = tid & 63;
    const int b   = blockIdx.x >> 9;               // 512 blocks per batch
    const int i   = ((blockIdx.x & 511) << 2) + wv;
    const int row = b * NL + i;

    // ---- stage CA coords (block-wide, the only barrier) ----
    const float* Xbatch = X + (size_t)b * NL * 12;
    for (int j = tid; j < NL; j += 256) {
        const float* p = Xbatch + (size_t)j * 12 + 3;
        Xs[j * 3 + 0] = p[0];
        Xs[j * 3 + 1] = p[1];
        Xs[j * 3 + 2] = p[2];
    }
    __syncthreads();

    const float* Mrow = mask + (size_t)b * NL;
    const float xi = Xs[i * 3], yi = Xs[i * 3 + 1], zi = Xs[i * 3 + 2];
    const float mi = Mrow[i];

    for (int q = ln; q < BINS; q += 64) hist[wv][q] = 0u;

    // ---- P1: row max ----
    float lmax = 0.0f;
    for (int j = ln; j < NL; j += 64)
        lmax = fmaxf(lmax, calc_d(Xs, Mrow, j, xi, yi, zi, mi));
    #pragma unroll
    for (int off = 32; off; off >>= 1) lmax = fmaxf(lmax, __shfl_xor(lmax, off));
    const float dmaxp1 = __fadd_rn(lmax, 1.0f);

    // ---- P2: histogram of adjusted-distance bits ----
    for (int j = ln; j < NL; j += 64) {
        unsigned int bits = calc_adj_bits(Xs, Mrow, j, xi, yi, zi, mi, dmaxp1);
        atomicAdd(&hist[wv][bits >> 21], 1u);
    }

    // ---- P3: wave scan over 1024 bins -> cutoff bin ----
    unsigned int hloc[16];
    unsigned int lsum = 0;
    #pragma unroll
    for (int q = 0; q < 16; ++q) { hloc[q] = hist[wv][ln * 16 + q]; lsum += hloc[q]; }
    unsigned int run = lsum;
    #pragma unroll
    for (int off = 1; off < 64; off <<= 1) {
        unsigned int o = __shfl_up(run, off);
        if (ln >= off) run += o;
    }
    const unsigned int excl = run - lsum;
    const bool found = (excl < TOPK) && (run >= TOPK);
    ull fm = __ballot(found);
    unsigned int cb = 0;
    if (found) {
        unsigned int r = excl;
        #pragma unroll
        for (int q = 0; q < 16; ++q) {
            unsigned int h = hloc[q];
            if (r < TOPK && r + h >= TOPK) cb = (unsigned)(ln * 16 + q);
            r += h;
        }
    }
    const int fl = (int)__builtin_ctzll(fm);
    const unsigned int cutBin = __shfl(cb, fl);

    // ---- P4: ordered ballot compaction ----
    unsigned int base = 0;
    for (int j = ln; j < NL; j += 64) {
        unsigned int bits = calc_adj_bits(Xs, Mrow, j, xi, yi, zi, mi, dmaxp1);
        bool act = (bits >> 21) <= cutBin;
        ull m = __ballot(act);
        if (act) {
            unsigned int pos = base + (unsigned)__popcll(m & ((1ull << ln) - 1ull));
            if (pos < CAND_CAP) cand[wv][pos] = ((ull)bits << 32) | (unsigned)j;
        }
        base += (unsigned)__popcll(m);
    }
    const unsigned int cnt = base;

    float* eo  = eidx + (size_t)row * TOPK;
    float* dno = dnb  + (size_t)row * TOPK;

    if (cnt <= CAND_CAP) {
        // ---- P5: rank-based exact selection ----
        ull k0 = ((unsigned)ln        < cnt) ? cand[wv][ln]        : ~0ULL;
        ull k1 = ((unsigned)ln +  64u < cnt) ? cand[wv][ln +  64]  : ~0ULL;
        ull k2 = ((unsigned)ln + 128u < cnt) ? cand[wv][ln + 128]  : ~0ULL;
        ull k3 = ((unsigned)ln + 192u < cnt) ? cand[wv][ln + 192]  : ~0ULL;
        int r0 = 0, r1 = 0, r2 = 0, r3 = 0;
        for (unsigned int p = 0; p < cnt; ++p) {
            ull kp = cand[wv][p];
            r0 += (kp < k0); r1 += (kp < k1); r2 += (kp < k2); r3 += (kp < k3);
        }
        if (r0 < TOPK) { eo[r0] = (float)(unsigned)(k0 & 0xFFFFFFFFu); dno[r0] = __uint_as_float((unsigned)(k0 >> 32)); }
        if (r1 < TOPK) { eo[r1] = (float)(unsigned)(k1 & 0xFFFFFFFFu); dno[r1] = __uint_as_float((unsigned)(k1 >> 32)); }
        if (r2 < TOPK) { eo[r2] = (float)(unsigned)(k2 & 0xFFFFFFFFu); dno[r2] = __uint_as_float((unsigned)(k2 >> 32)); }
        if (r3 < TOPK) { eo[r3] = (float)(unsigned)(k3 & 0xFFFFFFFFu); dno[r3] = __uint_as_float((unsigned)(k3 >> 32)); }
    } else {
        // ---- fallback: wave-iterative exact argmin (rare; correctness only) ----
        ull last = 0ULL;
        for (int k = 0; k < TOPK; ++k) {
            ull best = ~0ULL;
            for (int j = ln; j < NL; j += 64) {
                unsigned int bits = calc_adj_bits(Xs, Mrow, j, xi, yi, zi, mi, dmaxp1);
                ull key = ((ull)bits << 32) | (unsigned)j;
                if (key > last && key < best) best = key;
            }
            #pragma unroll
            for (int off = 32; off; off >>= 1) {
                ull o = __shfl_xor(best, off);
                if (o < best) best = o;
            }
            if (ln == 0) {
                eo[k]  = (float)(unsigned)(best & 0xFFFFFFFFu);
                dno[k] = __uint_as_float((unsigned)(best >> 32));
            }
            last = best;
        }
    }
}

// ---------------------------------------------------------------------------
// K2: edge features -> 32x128 matmul (MFMA bf16) -> LayerNorm -> E.
// One wave per 16-edge tile. (unchanged from R2)
// ---------------------------------------------------------------------------
__global__ __launch_bounds__(256) void edge_kernel(
    const float* __restrict__ eidx, const float* __restrict__ dnb,
    const float* __restrict__ We, const float* __restrict__ be,
    const float* __restrict__ ge, const float* __restrict__ bte,
    float* __restrict__ E)
{
    const int lane = threadIdx.x & 63;
    const int c    = lane & 15;        // A-row (edge) / D-col
    const int g    = lane >> 4;        // k-group
    const int wid  = (int)((blockIdx.x * blockDim.x + threadIdx.x) >> 6);
    const int nw   = (int)((gridDim.x * blockDim.x) >> 6);

    short8v B[8];
    #pragma unroll
    for (int t = 0; t < 8; ++t)
        #pragma unroll
        for (int e = 0; e < 8; ++e)
            B[t][e] = f2bf(We[(g * 8 + e) * NH + t * 16 + c]);

    float bias[8], gam[8], bet[8];
    #pragma unroll
    for (int t = 0; t < 8; ++t) {
        bias[t] = be [t * 16 + c];
        gam[t]  = ge [t * 16 + c];
        bet[t]  = bte[t * 16 + c];
    }

    float fcs[8];
    #pragma unroll
    for (int e = 0; e < 8; ++e) {
        if (g < 2) fcs[e] = expf((float)(2 * e) * -0.57564627f);  // ln(1e4)/16
        else       fcs[e] = (float)((g - 2) * 8 + e) * (20.0f / 15.0f);
    }

    const int ntiles = NB * NL * TOPK / 16;
    for (int tile = wid; tile < ntiles; tile += nw) {
        const int e0 = tile * 16;
        const int eg = e0 + c;
        const float fidx = eidx[eg];
        const float Dv   = dnb[eg];
        const int   row  = eg / TOPK;
        const float d    = fidx - (float)(row & (NL - 1));

        short8v A;
        if (g == 0) {
            #pragma unroll
            for (int e = 0; e < 8; ++e) A[e] = f2bf(cosf(d * fcs[e]));
        } else if (g == 1) {
            #pragma unroll
            for (int e = 0; e < 8; ++e) A[e] = f2bf(sinf(d * fcs[e]));
        } else {
            #pragma unroll
            for (int e = 0; e < 8; ++e) {
                float tt = (Dv - fcs[e]) * 0.8f;
                A[e] = f2bf(expf(-tt * tt));
            }
        }

        f32x4 acc[8];
        const f32x4 zero = {0.0f, 0.0f, 0.0f, 0.0f};
        #pragma unroll
        for (int t = 0; t < 8; ++t)
            acc[t] = __builtin_amdgcn_mfma_f32_16x16x32_bf16(A, B[t], zero, 0, 0, 0);

        float s[4]  = {0, 0, 0, 0};
        float s2[4] = {0, 0, 0, 0};
        #pragma unroll
        for (int t = 0; t < 8; ++t)
            #pragma unroll
            for (int j = 0; j < 4; ++j) {
                float v = acc[t][j] + bias[t];
                acc[t][j] = v;
                s[j]  += v;
                s2[j] = fmaf(v, v, s2[j]);
            }
        #pragma unroll
        for (int j = 0; j < 4; ++j)
            #pragma unroll
            for (int off = 1; off < 16; off <<= 1) {
                s[j]  += __shfl_xor(s[j],  off);
                s2[j] += __shfl_xor(s2[j], off);
            }
        float mean[4], inv[4];
        #pragma unroll
        for (int j = 0; j < 4; ++j) {
            mean[j] = s[j] * (1.0f / 128.0f);
            float var = fmaxf(s2[j] * (1.0f / 128.0f) - mean[j] * mean[j], 0.0f);
            inv[j] = rsqrtf(var + 1e-5f);
        }
        #pragma unroll
        for (int t = 0; t < 8; ++t)
            #pragma unroll
            for (int j = 0; j < 4; ++j) {
                float v = (acc[t][j] - mean[j]) * inv[j] * gam[t] + bet[t];
                __builtin_nontemporal_store(
                    v, &E[(size_t)(e0 + g * 4 + j) * NH + t * 16 + c]);
            }
    }
}

// ---------------------------------------------------------------------------
// K3a: dihedral angle features (6 per node) into workspace.
// ---------------------------------------------------------------------------
__device__ __forceinline__ void loadPt(const float* XB, int t, float v[3]) {
    int r = t / 3, a = t - 3 * r;
    const float* p = XB + ((size_t)r * 4 + a) * 3;
    v[0] = p[0]; v[1] = p[1]; v[2] = p[2];
}
__device__ __forceinline__ void unit3(float v[3]) {
    float n = sqrtf(v[0]*v[0] + v[1]*v[1] + v[2]*v[2]) + 1e-8f;
    v[0] /= n; v[1] /= n; v[2] /= n;
}
__device__ __forceinline__ void cross3(const float a[3], const float b[3], float o[3]) {
    o[0] = a[1]*b[2] - a[2]*b[1];
    o[1] = a[2]*b[0] - a[0]*b[2];
    o[2] = a[0]*b[1] - a[1]*b[0];
}

__global__ __launch_bounds__(256) void dihedral_kernel(
    const float* __restrict__ X, float* __restrict__ nf)
{
    int node = blockIdx.x * blockDim.x + threadIdx.x;
    if (node >= NB * NL) return;
    int b = node >> 11, i = node & (NL - 1);
    const float* XB = X + (size_t)b * NL * 12;

    float ang[3];
    #pragma unroll
    for (int a = 0; a < 3; ++a) {
        int t = 3 * i - 1 + a;
        float an = 0.0f;
        if (t >= 0 && t <= 3 * NL - 4) {
            float p0[3], p1[3], p2[3], p3[3];
            loadPt(XB, t, p0); loadPt(XB, t + 1, p1);
            loadPt(XB, t + 2, p2); loadPt(XB, t + 3, p3);
            float u2[3], u1[3], u0[3];
            for (int cc = 0; cc < 3; ++cc) {
                u2[cc] = p1[cc] - p0[cc];
                u1[cc] = p2[cc] - p1[cc];
                u0[cc] = p3[cc] - p2[cc];
            }
            unit3(u2); unit3(u1); unit3(u0);
            float n2[3], n1[3];
            cross3(u2, u1, n2); cross3(u1, u0, n1);
            unit3(n2); unit3(n1);
            float cosD = n2[0]*n1[0] + n2[1]*n1[1] + n2[2]*n1[2];
            cosD = fminf(fmaxf(cosD, -1.0f + 1e-7f), 1.0f - 1e-7f);
            float sg = u2[0]*n1[0] + u2[1]*n1[1] + u2[2]*n1[2];
            float sgn = (sg > 0.0f) ? 1.0f : ((sg < 0.0f) ? -1.0f : 0.0f);
            an = sgn * acosf(cosD);
        }
        ang[a] = an;
    }
    float* o = nf + (size_t)node * 6;
    o[0] = cosf(ang[0]); o[1] = cosf(ang[1]); o[2] = cosf(ang[2]);
    o[3] = sinf(ang[0]); o[4] = sinf(ang[1]); o[5] = sinf(ang[2]);
}

// ---------------------------------------------------------------------------
// K3b: node 6x128 matmul + LayerNorm -> V. One wave per node.
// ---------------------------------------------------------------------------
__global__ __launch_bounds__(256) void node_kernel(
    const float* __restrict__ nf, const float* __restrict__ Wn,
    const float* __restrict__ bn, const float* __restrict__ gn,
    const float* __restrict__ btn, float* __restrict__ V)
{
    const int lane = threadIdx.x & 63;
    const int wid  = (int)((blockIdx.x * blockDim.x + threadIdx.x) >> 6);
    const int nw   = (int)((gridDim.x * blockDim.x) >> 6);
    const int h0 = lane, h1 = lane + 64;

    float w0[6], w1[6];
    #pragma unroll
    for (int j = 0; j < 6; ++j) { w0[j] = Wn[j * NH + h0]; w1[j] = Wn[j * NH + h1]; }
    const float bb0 = bn[h0],  bb1 = bn[h1];
    const float g0  = gn[h0],  g1  = gn[h1];
    const float t0  = btn[h0], t1  = btn[h1];

    for (int n = wid; n < NB * NL; n += nw) {
        float a0 = bb0, a1 = bb1;
        #pragma unroll
        for (int j = 0; j < 6; ++j) {
            float f = nf[(size_t)n * 6 + j];
            a0 = fmaf(f, w0[j], a0);
            a1 = fmaf(f, w1[j], a1);
        }
        float s  = a0 + a1;
        float s2 = fmaf(a0, a0, a1 * a1);
        #pragma unroll
        for (int off = 32; off; off >>= 1) {
            s  += __shfl_xor(s, off);
            s2 += __shfl_xor(s2, off);
        }
        float mean = s * (1.0f / 128.0f);
        float var  = fmaxf(s2 * (1.0f / 128.0f) - mean * mean, 0.0f);
        float inv  = rsqrtf(var + 1e-5f);
        float* o = V + (size_t)n * NH;
        o[h0] = (a0 - mean) * inv * g0 + t0;
        o[h1] = (a1 - mean) * inv * g1 + t1;
    }
}

extern "C" void kernel_launch(void* const* d_in, const int* in_sizes, int n_in,
                              void* d_out, int out_size, void* d_ws, size_t ws_size,
                              hipStream_t stream)
{
    const float* X    = (const float*)d_in[0];
    const float* mask = (const float*)d_in[1];
    const float* Wn   = (const float*)d_in[2];
    const float* bn   = (const float*)d_in[3];
    const float* We   = (const float*)d_in[4];
    const float* be   = (const float*)d_in[5];
    const float* gn   = (const float*)d_in[6];
    const float* btn  = (const float*)d_in[7];
    const float* ge   = (const float*)d_in[8];
    const float* bte  = (const float*)d_in[9];

    float* out = (float*)d_out;
    float* V   = out;                                   // (8,2048,128)
    float* E   = V  + (size_t)NB * NL * NH;             // (8,2048,30,128)
    float* EI  = E  + (size_t)NB * NL * TOPK * NH;      // (8,2048,30) as float

    float* dnb = (float*)d_ws;                          // D_neighbors scratch
    float* nf  = dnb + (size_t)NB * NL * TOPK;          // node features scratch

    hipLaunchKernelGGL(topk_kernel,     dim3(NB * NL / 4),         dim3(256), 0, stream,
                       X, mask, EI, dnb);
    hipLaunchKernelGGL(dihedral_kernel, dim3((NB * NL + 255)/256), dim3(256), 0, stream,
                       X, nf);
    hipLaunchKernelGGL(edge_kernel,     dim3(1920),                dim3(256), 0, stream,
                       EI, dnb, We, be, ge, bte, E);
    hipLaunchKernelGGL(node_kernel,     dim3(64),                  dim3(256), 0, stream,
                       nf, Wn, bn, gn, btn, V);
}

// Round 5
// 188.323 us; speedup vs baseline: 3.5958x; 1.2752x over previous
//
#include <hip/hip_runtime.h>
#include <cstdint>
#include <cstddef>

#define NB 8
#define NL 2048
#define TOPK 30
#define NH 128
#define CAND_CAP 256
#define BINS 1024

typedef unsigned long long ull;
typedef __attribute__((ext_vector_type(8))) short short8v;   // 8 bf16
typedef __attribute__((ext_vector_type(4))) float f32x4;

__device__ __forceinline__ short f2bf(float f) {
    unsigned int b = __float_as_uint(f);
    b += 0x7fffu + ((b >> 16) & 1u);          // round-to-nearest-even
    return (short)(b >> 16);
}

// ---------------------------------------------------------------------------
// K0: pack CA coords + mask into SoA float4 (x,y,z,m) for coalesced topk loads.
// ---------------------------------------------------------------------------
__global__ __launch_bounds__(256) void xpose_kernel(
    const float* __restrict__ X, const float* __restrict__ mask,
    float4* __restrict__ P)
{
    int t = blockIdx.x * blockDim.x + threadIdx.x;
    if (t >= NB * NL) return;
    const float* p = X + (size_t)t * 12 + 3;
    P[t] = make_float4(p[0], p[1], p[2], mask[t]);
}

// ---------------------------------------------------------------------------
// K1: one WAVE per row, fully register-resident. Each lane owns 32 points:
// one coalesced float4 load each, distance computed ONCE into VGPRs
// (bit-exact vs numpy: ((dx*dx+dy*dy)+dz*dz)+1e-6, rn sqrt), then max-reduce,
// in-register adjust -> bits, 1024-bin LDS histogram, wave shuffle scan ->
// cutoff, ballot compaction, rank-based exact selection.
// Key = (bits << 32) | j  == lax.top_k stable tie order.
// ---------------------------------------------------------------------------
__global__ __launch_bounds__(256) void topk_kernel(
    const float4* __restrict__ P,
    float* __restrict__ eidx, float* __restrict__ dnb)
{
    __shared__ unsigned int hist[4][BINS];         // 16 KB
    __shared__ ull cand[4][CAND_CAP];              // 8 KB

    const int tid = threadIdx.x;
    const int wv  = tid >> 6;
    const int ln  = tid & 63;
    const int row = blockIdx.x * 4 + wv;           // 4 consecutive rows/block
    const int b   = row >> 11;
    const int i   = row & (NL - 1);

    const float4* Pb = P + (size_t)b * NL;
    const float4 pi = Pb[i];
    const float xi = pi.x, yi = pi.y, zi = pi.z, mi = pi.w;

    #pragma unroll
    for (int q = 0; q < 16; ++q) hist[wv][ln + 64 * q] = 0u;

    // ---- P1: distances once, register-resident ----
    float dv[32], m2v[32];
    float lmax = 0.0f;
    #pragma unroll
    for (int t = 0; t < 32; ++t) {
        const int j = ln + 64 * t;
        const float4 pj = Pb[j];
        float dx = xi - pj.x;
        float dy = yi - pj.y;
        float dz = zi - pj.z;
        float s = __fadd_rn(__fmul_rn(dx, dx), __fmul_rn(dy, dy));
        s = __fadd_rn(s, __fmul_rn(dz, dz));
        s = __fadd_rn(s, 1e-6f);
        float m2 = __fmul_rn(pj.w, mi);
        float d  = __fmul_rn(m2, __fsqrt_rn(s));
        dv[t] = d; m2v[t] = m2;
        lmax = fmaxf(lmax, d);
    }
    #pragma unroll
    for (int off = 32; off; off >>= 1) lmax = fmaxf(lmax, __shfl_xor(lmax, off));
    const float dmaxp1 = __fadd_rn(lmax, 1.0f);

    // ---- P2: adjust in-register + histogram ----
    unsigned int bits[32];
    #pragma unroll
    for (int t = 0; t < 32; ++t) {
        bits[t] = __float_as_uint(
            __fadd_rn(dv[t], __fmul_rn(__fsub_rn(1.0f, m2v[t]), dmaxp1)));
        atomicAdd(&hist[wv][bits[t] >> 21], 1u);
    }

    // ---- P3: wave scan over 1024 bins -> cutoff bin ----
    unsigned int hloc[16];
    unsigned int lsum = 0;
    #pragma unroll
    for (int q = 0; q < 16; ++q) { hloc[q] = hist[wv][ln * 16 + q]; lsum += hloc[q]; }
    unsigned int run = lsum;
    #pragma unroll
    for (int off = 1; off < 64; off <<= 1) {
        unsigned int o = __shfl_up(run, off);
        if (ln >= off) run += o;
    }
    const unsigned int excl = run - lsum;
    const bool found = (excl < TOPK) && (run >= TOPK);
    ull fm = __ballot(found);
    unsigned int cb = 0;
    if (found) {
        unsigned int r = excl;
        #pragma unroll
        for (int q = 0; q < 16; ++q) {
            unsigned int h = hloc[q];
            if (r < TOPK && r + h >= TOPK) cb = (unsigned)(ln * 16 + q);
            r += h;
        }
    }
    const int fl = (int)__builtin_ctzll(fm);
    const unsigned int cutBin = __shfl(cb, fl);

    // ---- P4: ordered ballot compaction (from registers) ----
    unsigned int base = 0;
    #pragma unroll
    for (int t = 0; t < 32; ++t) {
        bool act = (bits[t] >> 21) <= cutBin;
        ull m = __ballot(act);
        if (act) {
            unsigned int pos = base + (unsigned)__popcll(m & ((1ull << ln) - 1ull));
            if (pos < CAND_CAP)
                cand[wv][pos] = ((ull)bits[t] << 32) | (unsigned)(ln + 64 * t);
        }
        base += (unsigned)__popcll(m);
    }
    const unsigned int cnt = base;

    float* eo  = eidx + (size_t)row * TOPK;
    float* dno = dnb  + (size_t)row * TOPK;

    if (cnt <= CAND_CAP) {
        // ---- P5: rank-based exact selection ----
        ull k0 = ((unsigned)ln        < cnt) ? cand[wv][ln]        : ~0ULL;
        ull k1 = ((unsigned)ln +  64u < cnt) ? cand[wv][ln +  64]  : ~0ULL;
        ull k2 = ((unsigned)ln + 128u < cnt) ? cand[wv][ln + 128]  : ~0ULL;
        ull k3 = ((unsigned)ln + 192u < cnt) ? cand[wv][ln + 192]  : ~0ULL;
        int r0 = 0, r1 = 0, r2 = 0, r3 = 0;
        for (unsigned int p = 0; p < cnt; ++p) {
            ull kp = cand[wv][p];
            r0 += (kp < k0); r1 += (kp < k1); r2 += (kp < k2); r3 += (kp < k3);
        }
        if (r0 < TOPK) { eo[r0] = (float)(unsigned)(k0 & 0xFFFFFFFFu); dno[r0] = __uint_as_float((unsigned)(k0 >> 32)); }
        if (r1 < TOPK) { eo[r1] = (float)(unsigned)(k1 & 0xFFFFFFFFu); dno[r1] = __uint_as_float((unsigned)(k1 >> 32)); }
        if (r2 < TOPK) { eo[r2] = (float)(unsigned)(k2 & 0xFFFFFFFFu); dno[r2] = __uint_as_float((unsigned)(k2 >> 32)); }
        if (r3 < TOPK) { eo[r3] = (float)(unsigned)(k3 & 0xFFFFFFFFu); dno[r3] = __uint_as_float((unsigned)(k3 >> 32)); }
    } else {
        // ---- fallback: wave-iterative exact argmin from registers (rare) ----
        ull last = 0ULL;
        for (int k = 0; k < TOPK; ++k) {
            ull best = ~0ULL;
            #pragma unroll
            for (int t = 0; t < 32; ++t) {
                ull key = ((ull)bits[t] << 32) | (unsigned)(ln + 64 * t);
                if (key > last && key < best) best = key;
            }
            #pragma unroll
            for (int off = 32; off; off >>= 1) {
                ull o = __shfl_xor(best, off);
                if (o < best) best = o;
            }
            if (ln == 0) {
                eo[k]  = (float)(unsigned)(best & 0xFFFFFFFFu);
                dno[k] = __uint_as_float((unsigned)(best >> 32));
            }
            last = best;
        }
    }
}

// ---------------------------------------------------------------------------
// K2: edge features -> 32x128 matmul (MFMA bf16) -> LayerNorm -> E.
// One wave per 16-edge tile. (unchanged from R2)
// ---------------------------------------------------------------------------
__global__ __launch_bounds__(256) void edge_kernel(
    const float* __restrict__ eidx, const float* __restrict__ dnb,
    const float* __restrict__ We, const float* __restrict__ be,
    const float* __restrict__ ge, const float* __restrict__ bte,
    float* __restrict__ E)
{
    const int lane = threadIdx.x & 63;
    const int c    = lane & 15;        // A-row (edge) / D-col
    const int g    = lane >> 4;        // k-group
    const int wid  = (int)((blockIdx.x * blockDim.x + threadIdx.x) >> 6);
    const int nw   = (int)((gridDim.x * blockDim.x) >> 6);

    short8v B[8];
    #pragma unroll
    for (int t = 0; t < 8; ++t)
        #pragma unroll
        for (int e = 0; e < 8; ++e)
            B[t][e] = f2bf(We[(g * 8 + e) * NH + t * 16 + c]);

    float bias[8], gam[8], bet[8];
    #pragma unroll
    for (int t = 0; t < 8; ++t) {
        bias[t] = be [t * 16 + c];
        gam[t]  = ge [t * 16 + c];
        bet[t]  = bte[t * 16 + c];
    }

    float fcs[8];
    #pragma unroll
    for (int e = 0; e < 8; ++e) {
        if (g < 2) fcs[e] = expf((float)(2 * e) * -0.57564627f);  // ln(1e4)/16
        else       fcs[e] = (float)((g - 2) * 8 + e) * (20.0f / 15.0f);
    }

    const int ntiles = NB * NL * TOPK / 16;
    for (int tile = wid; tile < ntiles; tile += nw) {
        const int e0 = tile * 16;
        const int eg = e0 + c;
        const float fidx = eidx[eg];
        const float Dv   = dnb[eg];
        const int   row  = eg / TOPK;
        const float d    = fidx - (float)(row & (NL - 1));

        short8v A;
        if (g == 0) {
            #pragma unroll
            for (int e = 0; e < 8; ++e) A[e] = f2bf(cosf(d * fcs[e]));
        } else if (g == 1) {
            #pragma unroll
            for (int e = 0; e < 8; ++e) A[e] = f2bf(sinf(d * fcs[e]));
        } else {
            #pragma unroll
            for (int e = 0; e < 8; ++e) {
                float tt = (Dv - fcs[e]) * 0.8f;
                A[e] = f2bf(expf(-tt * tt));
            }
        }

        f32x4 acc[8];
        const f32x4 zero = {0.0f, 0.0f, 0.0f, 0.0f};
        #pragma unroll
        for (int t = 0; t < 8; ++t)
            acc[t] = __builtin_amdgcn_mfma_f32_16x16x32_bf16(A, B[t], zero, 0, 0, 0);

        float s[4]  = {0, 0, 0, 0};
        float s2[4] = {0, 0, 0, 0};
        #pragma unroll
        for (int t = 0; t < 8; ++t)
            #pragma unroll
            for (int j = 0; j < 4; ++j) {
                float v = acc[t][j] + bias[t];
                acc[t][j] = v;
                s[j]  += v;
                s2[j] = fmaf(v, v, s2[j]);
            }
        #pragma unroll
        for (int j = 0; j < 4; ++j)
            #pragma unroll
            for (int off = 1; off < 16; off <<= 1) {
                s[j]  += __shfl_xor(s[j],  off);
                s2[j] += __shfl_xor(s2[j], off);
            }
        float mean[4], inv[4];
        #pragma unroll
        for (int j = 0; j < 4; ++j) {
            mean[j] = s[j] * (1.0f / 128.0f);
            float var = fmaxf(s2[j] * (1.0f / 128.0f) - mean[j] * mean[j], 0.0f);
            inv[j] = rsqrtf(var + 1e-5f);
        }
        #pragma unroll
        for (int t = 0; t < 8; ++t)
            #pragma unroll
            for (int j = 0; j < 4; ++j) {
                float v = (acc[t][j] - mean[j]) * inv[j] * gam[t] + bet[t];
                __builtin_nontemporal_store(
                    v, &E[(size_t)(e0 + g * 4 + j) * NH + t * 16 + c]);
            }
    }
}

// ---------------------------------------------------------------------------
// K3a: dihedral angle features (6 per node) into workspace.
// ---------------------------------------------------------------------------
__device__ __forceinline__ void loadPt(const float* XB, int t, float v[3]) {
    int r = t / 3, a = t - 3 * r;
    const float* p = XB + ((size_t)r * 4 + a) * 3;
    v[0] = p[0]; v[1] = p[1]; v[2] = p[2];
}
__device__ __forceinline__ void unit3(float v[3]) {
    float n = sqrtf(v[0]*v[0] + v[1]*v[1] + v[2]*v[2]) + 1e-8f;
    v[0] /= n; v[1] /= n; v[2] /= n;
}
__device__ __forceinline__ void cross3(const float a[3], const float b[3], float o[3]) {
    o[0] = a[1]*b[2] - a[2]*b[1];
    o[1] = a[2]*b[0] - a[0]*b[2];
    o[2] = a[0]*b[1] - a[1]*b[0];
}

__global__ __launch_bounds__(256) void dihedral_kernel(
    const float* __restrict__ X, float* __restrict__ nf)
{
    int node = blockIdx.x * blockDim.x + threadIdx.x;
    if (node >= NB * NL) return;
    int b = node >> 11, i = node & (NL - 1);
    const float* XB = X + (size_t)b * NL * 12;

    float ang[3];
    #pragma unroll
    for (int a = 0; a < 3; ++a) {
        int t = 3 * i - 1 + a;
        float an = 0.0f;
        if (t >= 0 && t <= 3 * NL - 4) {
            float p0[3], p1[3], p2[3], p3[3];
            loadPt(XB, t, p0); loadPt(XB, t + 1, p1);
            loadPt(XB, t + 2, p2); loadPt(XB, t + 3, p3);
            float u2[3], u1[3], u0[3];
            for (int cc = 0; cc < 3; ++cc) {
                u2[cc] = p1[cc] - p0[cc];
                u1[cc] = p2[cc] - p1[cc];
                u0[cc] = p3[cc] - p2[cc];
            }
            unit3(u2); unit3(u1); unit3(u0);
            float n2[3], n1[3];
            cross3(u2, u1, n2); cross3(u1, u0, n1);
            unit3(n2); unit3(n1);
            float cosD = n2[0]*n1[0] + n2[1]*n1[1] + n2[2]*n1[2];
            cosD = fminf(fmaxf(cosD, -1.0f + 1e-7f), 1.0f - 1e-7f);
            float sg = u2[0]*n1[0] + u2[1]*n1[1] + u2[2]*n1[2];
            float sgn = (sg > 0.0f) ? 1.0f : ((sg < 0.0f) ? -1.0f : 0.0f);
            an = sgn * acosf(cosD);
        }
        ang[a] = an;
    }
    float* o = nf + (size_t)node * 6;
    o[0] = cosf(ang[0]); o[1] = cosf(ang[1]); o[2] = cosf(ang[2]);
    o[3] = sinf(ang[0]); o[4] = sinf(ang[1]); o[5] = sinf(ang[2]);
}

// ---------------------------------------------------------------------------
// K3b: node 6x128 matmul + LayerNorm -> V. One wave per node.
// ---------------------------------------------------------------------------
__global__ __launch_bounds__(256) void node_kernel(
    const float* __restrict__ nf, const float* __restrict__ Wn,
    const float* __restrict__ bn, const float* __restrict__ gn,
    const float* __restrict__ btn, float* __restrict__ V)
{
    const int lane = threadIdx.x & 63;
    const int wid  = (int)((blockIdx.x * blockDim.x + threadIdx.x) >> 6);
    const int nw   = (int)((gridDim.x * blockDim.x) >> 6);
    const int h0 = lane, h1 = lane + 64;

    float w0[6], w1[6];
    #pragma unroll
    for (int j = 0; j < 6; ++j) { w0[j] = Wn[j * NH + h0]; w1[j] = Wn[j * NH + h1]; }
    const float bb0 = bn[h0],  bb1 = bn[h1];
    const float g0  = gn[h0],  g1  = gn[h1];
    const float t0  = btn[h0], t1  = btn[h1];

    for (int n = wid; n < NB * NL; n += nw) {
        float a0 = bb0, a1 = bb1;
        #pragma unroll
        for (int j = 0; j < 6; ++j) {
            float f = nf[(size_t)n * 6 + j];
            a0 = fmaf(f, w0[j], a0);
            a1 = fmaf(f, w1[j], a1);
        }
        float s  = a0 + a1;
        float s2 = fmaf(a0, a0, a1 * a1);
        #pragma unroll
        for (int off = 32; off; off >>= 1) {
            s  += __shfl_xor(s, off);
            s2 += __shfl_xor(s2, off);
        }
        float mean = s * (1.0f / 128.0f);
        float var  = fmaxf(s2 * (1.0f / 128.0f) - mean * mean, 0.0f);
        float inv  = rsqrtf(var + 1e-5f);
        float* o = V + (size_t)n * NH;
        o[h0] = (a0 - mean) * inv * g0 + t0;
        o[h1] = (a1 - mean) * inv * g1 + t1;
    }
}

extern "C" void kernel_launch(void* const* d_in, const int* in_sizes, int n_in,
                              void* d_out, int out_size, void* d_ws, size_t ws_size,
                              hipStream_t stream)
{
    const float* X    = (const float*)d_in[0];
    const float* mask = (const float*)d_in[1];
    const float* Wn   = (const float*)d_in[2];
    const float* bn   = (const float*)d_in[3];
    const float* We   = (const float*)d_in[4];
    const float* be   = (const float*)d_in[5];
    const float* gn   = (const float*)d_in[6];
    const float* btn  = (const float*)d_in[7];
    const float* ge   = (const float*)d_in[8];
    const float* bte  = (const float*)d_in[9];

    float* out = (float*)d_out;
    float* V   = out;                                   // (8,2048,128)
    float* E   = V  + (size_t)NB * NL * NH;             // (8,2048,30,128)
    float* EI  = E  + (size_t)NB * NL * TOPK * NH;      // (8,2048,30) as float

    float4* P  = (float4*)d_ws;                         // SoA (x,y,z,m), 256 KB
    float* dnb = (float*)d_ws + 4 * (size_t)NB * NL;    // D_neighbors scratch
    float* nf  = dnb + (size_t)NB * NL * TOPK;          // node features scratch

    hipLaunchKernelGGL(xpose_kernel,    dim3((NB * NL + 255)/256), dim3(256), 0, stream,
                       X, mask, P);
    hipLaunchKernelGGL(topk_kernel,     dim3(NB * NL / 4),         dim3(256), 0, stream,
                       P, EI, dnb);
    hipLaunchKernelGGL(dihedral_kernel, dim3((NB * NL + 255)/256), dim3(256), 0, stream,
                       X, nf);
    hipLaunchKernelGGL(edge_kernel,     dim3(1920),                dim3(256), 0, stream,
                       EI, dnb, We, be, ge, bte, E);
    hipLaunchKernelGGL(node_kernel,     dim3(256),                 dim3(256), 0, stream,
                       nf, Wn, bn, gn, btn, V);
}